// Round 14
// baseline (4150.460 us; speedup 1.0000x reference)
//
#include <hip/hip_runtime.h>
#include <math.h>

#define NN 100000
#define NE 1600000
#define NG 128
#define HD 128
#define WLK 16
#define NL 5
#define NOUT 10
#define BNEPS 1e-5f
#define CDIV(a,b) (((a)+(b)-1)/(b))

#define NBKT 782          // buckets of 128 nodes (col>>7)
#define NEB 400           // edge-blocks for bucketing
#define EPB 4000          // edges per edge-block (NEB*EPB == NE)
#define NSCAN (NBKT*NEB)  // 312800
#define NSB CDIV(NSCAN,1024)  // 306
#define NBM 782           // GEMM row-blocks (CDIV(NN,128))
#define NBRW 391          // rw blocks (CDIV(NN,256)) — co-resident (<< 2048 capacity)

typedef float f32x4 __attribute__((ext_vector_type(4)));
typedef _Float16 f16x8 __attribute__((ext_vector_type(8)));
typedef unsigned short ushort_t;
typedef unsigned int uint_t;

__device__ __forceinline__ ushort_t f2h(float x) {
    union { _Float16 h; ushort_t u; } c;
    c.h = (_Float16)x;                     // v_cvt_f16_f32, RNE
    return c.u;
}
__device__ __forceinline__ float h2f(ushort_t u) {
    union { ushort_t u; _Float16 h; } c;
    c.u = u;
    return (float)c.h;
}

// ---------------- graph counts + start offsets via binary search (batch sorted) ----------------
__global__ void k_cnt(const int* __restrict__ batch, int* __restrict__ cnt,
                      int* __restrict__ goff) {
    int g = threadIdx.x;
    if (g >= NG) return;
    int lo0 = 0, hi0 = NN;
    while (lo0 < hi0) { int m = (lo0 + hi0) >> 1; if (batch[m] < g) lo0 = m + 1; else hi0 = m; }
    int lo1 = lo0, hi1 = NN;
    while (lo1 < hi1) { int m = (lo1 + hi1) >> 1; if (batch[m] < g + 1) lo1 = m + 1; else hi1 = m; }
    cnt[g] = lo1 - lo0;
    goff[g] = lo0;
}

// ---------------- atomic-free CSR build: bucket histogram ----------------
__global__ void k_bhist(const int* __restrict__ col0, int* __restrict__ bhist) {
    __shared__ int hist[NBKT];
    for (int i = threadIdx.x; i < NBKT; i += 256) hist[i] = 0;
    __syncthreads();
    int e0 = blockIdx.x * EPB;
    for (int e = e0 + threadIdx.x; e < e0 + EPB; e += 256) atomicAdd(&hist[col0[e] >> 7], 1);
    __syncthreads();
    for (int i = threadIdx.x; i < NBKT; i += 256) bhist[i * NEB + blockIdx.x] = hist[i];
}

__global__ void k_gscan1(const int* __restrict__ in, int* __restrict__ bsum) {
    __shared__ int sm[256];
    int base = blockIdx.x * 1024 + threadIdx.x * 4;
    int s = 0;
#pragma unroll
    for (int i = 0; i < 4; ++i) { int e = base + i; if (e < NSCAN) s += in[e]; }
    sm[threadIdx.x] = s; __syncthreads();
    for (int st = 128; st > 0; st >>= 1) {
        if (threadIdx.x < st) sm[threadIdx.x] += sm[threadIdx.x + st];
        __syncthreads();
    }
    if (threadIdx.x == 0) bsum[blockIdx.x] = sm[0];
}

__global__ void k_scan2(int* __restrict__ blksum, int nblk) {
    __shared__ int sm[512];
    int t = threadIdx.x;
    int x = (t < nblk) ? blksum[t] : 0;
    sm[t] = x; __syncthreads();
    for (int s = 1; s < 512; s <<= 1) {
        int v = (t >= s) ? sm[t - s] : 0;
        __syncthreads();
        sm[t] += v;
        __syncthreads();
    }
    if (t < nblk) blksum[t] = sm[t] - x;   // exclusive
}

__global__ void k_gscan3(const int* __restrict__ in, const int* __restrict__ bsum,
                         int* __restrict__ out) {
    __shared__ int sm[256];
    int t = threadIdx.x;
    int base = blockIdx.x * 1024 + t * 4;
    int v[4]; int s = 0;
#pragma unroll
    for (int i = 0; i < 4; ++i) { int e = base + i; v[i] = (e < NSCAN) ? in[e] : 0; s += v[i]; }
    sm[t] = s; __syncthreads();
    for (int st = 1; st < 256; st <<= 1) {
        int x = (t >= st) ? sm[t - st] : 0;
        __syncthreads();
        sm[t] += x;
        __syncthreads();
    }
    int excl = sm[t] - s + bsum[blockIdx.x];
#pragma unroll
    for (int i = 0; i < 4; ++i) { int e = base + i; if (e < NSCAN) { out[e] = excl; excl += v[i]; } }
}

__global__ void k_escatter(const int* __restrict__ row0, const int* __restrict__ col0,
                           const int* __restrict__ boffs, int2* __restrict__ epair) {
    __shared__ int cur[NBKT];
    for (int i = threadIdx.x; i < NBKT; i += 256) cur[i] = boffs[i * NEB + blockIdx.x];
    __syncthreads();
    int e0 = blockIdx.x * EPB;
    for (int e = e0 + threadIdx.x; e < e0 + EPB; e += 256) {
        int c = col0[e], r = row0[e];
        int pos = atomicAdd(&cur[c >> 7], 1);
        epair[pos] = make_int2(c, r);
    }
}

__global__ void k_bucket(const int2* __restrict__ epair, const int* __restrict__ boffs,
                         int* __restrict__ rowptr, int* __restrict__ deg,
                         int* __restrict__ esrc) {
    __shared__ int cnt_[128], scn[128], cur_[128];
    int bkt = blockIdx.x, t = threadIdx.x;
    int bs = boffs[bkt * NEB];
    int be = (bkt + 1 < NBKT) ? boffs[(bkt + 1) * NEB] : NE;
    if (t < 128) cnt_[t] = 0;
    __syncthreads();
    for (int e = bs + t; e < be; e += 256) atomicAdd(&cnt_[epair[e].x & 127], 1);
    __syncthreads();
    int c = (t < 128) ? cnt_[t] : 0;
    if (t < 128) scn[t] = c;
    __syncthreads();
    for (int st = 1; st < 128; st <<= 1) {
        int x = (t >= st && t < 128) ? scn[t - st] : 0;
        __syncthreads();
        if (t < 128) scn[t] += x;
        __syncthreads();
    }
    if (t < 128) {
        int excl = scn[t] - c;
        int node = bkt * 128 + t;
        if (node < NN) { rowptr[node] = bs + excl; deg[node] = c; }
        cur_[t] = bs + excl;
    }
    if (bkt == NBKT - 1 && t == 0) rowptr[NN] = NE;
    __syncthreads();
    for (int e = bs + t; e < be; e += 256) {
        int2 p = epair[e];
        int pos = atomicAdd(&cur_[p.x & 127], 1);
        esrc[pos] = p.y;
    }
}

// ---------------- PE init ----------------
__global__ void k_init_pe(const int* __restrict__ deg, const int* __restrict__ batch,
                          const int* __restrict__ cnt, float* __restrict__ dinv,
                          float* __restrict__ p, float* __restrict__ pd) {
    int v = blockIdx.x * 256 + threadIdx.x;
    if (v >= NN) return;
    float dv = rsqrtf((float)(deg[v] + 1));   // +1: self-loop
    dinv[v] = dv;
    float pv = 1.0f / fmaxf((float)cnt[batch[v]], 1.0f);
    p[v] = pv; pd[v] = pv * dv;
}

// all 16 RW steps in one kernel; grid barrier via device-scope counters
// (391 blocks x 4 waves, zero LDS -> trivially co-resident on 256 CUs)
__global__ void k_rw_all(float* __restrict__ p0, float* __restrict__ p1,
                         float* __restrict__ pd0, float* __restrict__ pd1,
                         const int* __restrict__ rowptr, const int* __restrict__ esrc,
                         const float* __restrict__ dinv, float* __restrict__ rw,
                         int* __restrict__ ctr) {
    int v = blockIdx.x * 256 + threadIdx.x;
    bool act = (v < NN);
    int b = 0, e = 0;
    float dv = 0.f;
    if (act) { b = rowptr[v]; e = rowptr[v + 1]; dv = dinv[v]; }
    for (int s = 0; s < WLK; ++s) {
        const float* pin  = (s & 1) ? p1 : p0;
        const float* pdin = (s & 1) ? pd1 : pd0;
        float* pout  = (s & 1) ? p0 : p1;
        float* pdout = (s & 1) ? pd0 : pd1;
        if (act) {
            float a[8];
#pragma unroll
            for (int k = 0; k < 8; ++k) a[k] = 0.f;
            int i = b;
            for (; i + 8 <= e; i += 8) {
                int sv[8];
#pragma unroll
                for (int k = 0; k < 8; ++k) sv[k] = esrc[i + k];
#pragma unroll
                for (int k = 0; k < 8; ++k) a[k] += pdin[sv[k]];
            }
            for (; i < e; ++i) a[0] += pdin[esrc[i]];
            float sum = ((a[0] + a[1]) + (a[2] + a[3])) + ((a[4] + a[5]) + (a[6] + a[7]));
            float pv = pin[v];
            float np = sum * dv + pv * dv * dv;
            float nxt = 0.9f * np + 0.1f * pv;
            rw[(size_t)s * NN + v] = pv;
            pout[v] = nxt;
            pdout[v] = nxt * dv;
        }
        if (s == WLK - 1) break;
        // grid barrier: release writes, count in, spin until all blocks arrive
        __threadfence();
        __syncthreads();
        if (threadIdx.x == 0) {
            __hip_atomic_fetch_add(&ctr[s], 1, __ATOMIC_ACQ_REL, __HIP_MEMORY_SCOPE_AGENT);
            while (__hip_atomic_load(&ctr[s], __ATOMIC_ACQUIRE, __HIP_MEMORY_SCOPE_AGENT) < NBRW)
                __builtin_amdgcn_s_sleep(2);
        }
        __syncthreads();
    }
}

// also initializes the identity affine for layer-0 (A0=1, B0=0)
__global__ void k_mc1(const float* __restrict__ emb, const float* __restrict__ pe_w,
                      const float* __restrict__ pe_b, const float* __restrict__ proj_w,
                      const float* __restrict__ proj_b, float* __restrict__ M,
                      float* __restrict__ c1, float* __restrict__ bnA0,
                      float* __restrict__ bnB0) {
    int j = threadIdx.x;
    bnA0[j] = 1.f; bnB0[j] = 0.f;
    float c0 = proj_b[j];
    for (int d = 0; d < HD; ++d) c0 += emb[d] * proj_w[d * HD + j];
    for (int w = 0; w < WLK; ++w) c0 += pe_b[w] * proj_w[(HD + w) * HD + j];
    c1[j] = c0;
    for (int s = 0; s < WLK; ++s) {
        float m = 0.f;
        for (int w = 0; w < WLK; ++w) m += pe_w[s * WLK + w] * proj_w[(HD + w) * HD + j];
        M[s * HD + j] = m;
    }
}

// th0[v][cg..cg+3] = fp16(c1 + sum_s rw[s][v]*M[s][:])
__global__ void k_proj(const float* __restrict__ rw, const float* __restrict__ M,
                       const float* __restrict__ c1, uint2* __restrict__ th4) {
    int idx = blockIdx.x * 256 + threadIdx.x;   // NN*32
    if (idx >= NN * 32) return;
    int v = idx >> 5, cg = (idx & 31) * 4;
    float4 acc = *(const float4*)&c1[cg];
#pragma unroll
    for (int s = 0; s < WLK; ++s) {
        float r = rw[s * NN + v];
        float4 m = *(const float4*)&M[s * HD + cg];
        acc.x += r * m.x; acc.y += r * m.y; acc.z += r * m.z; acc.w += r * m.w;
    }
    th4[idx] = make_uint2((uint_t)f2h(acc.x) | ((uint_t)f2h(acc.y) << 16),
                          (uint_t)f2h(acc.z) | ((uint_t)f2h(acc.w) << 16));
}

// cast + transpose all GEMM weights to fp16 [n][k] once per call
__global__ void k_prepw(const float* __restrict__ g1, const float* __restrict__ g2,
                        const float* __restrict__ f1, const float* __restrict__ f2,
                        ushort_t* __restrict__ wt1, ushort_t* __restrict__ wt2,
                        ushort_t* __restrict__ wt3, ushort_t* __restrict__ wt4) {
    int i = blockIdx.x * 256 + threadIdx.x;   // 491520 total
    if (i < 81920) {
        int l = i >> 14, rem = i & 16383, n = rem >> 7, k = rem & 127;
        wt1[i] = f2h(g1[l * 16384 + k * 128 + n]);
    } else if (i < 163840) {
        int j = i - 81920;
        int l = j >> 14, rem = j & 16383, n = rem >> 7, k = rem & 127;
        wt2[j] = f2h(g2[l * 16384 + k * 128 + n]);
    } else if (i < 327680) {
        int j = i - 163840;
        int l = j >> 15, rem = j & 32767, n = rem >> 7, k = rem & 127;
        wt3[j] = f2h(f1[l * 32768 + k * 256 + n]);
    } else {
        int j = i - 327680;
        int l = j >> 15, rem = j & 32767, n = rem >> 8, k = rem & 255;
        wt4[j] = f2h(f2[l * 32768 + k * 128 + n]);
    }
}

// agg[v] = A0∘(t[v] + sum_j t[src_j]) + (deg+1)∘B0  (standalone, high-occupancy:
// round-8 lesson — fusing this latency-bound gather into the LDS-heavy GEMM
// kernel cut occupancy 68%→19% and tripled its cost)
__global__ void k_aggb(const uint_t* __restrict__ th2, const int* __restrict__ rowptr,
                       const int* __restrict__ esrc, const float* __restrict__ bnA0,
                       const float* __restrict__ bnB0, uint_t* __restrict__ aggb2) {
    int wave = threadIdx.x >> 6, lane = threadIdx.x & 63;
    int v = blockIdx.x * 4 + wave;
    if (v >= NN) return;
    uint_t u = th2[(size_t)v * 64 + lane];
    float sx[8], sy[8];
#pragma unroll
    for (int k = 0; k < 8; ++k) { sx[k] = 0.f; sy[k] = 0.f; }
    sx[0] = h2f((ushort_t)(u & 0xFFFFu)); sy[0] = h2f((ushort_t)(u >> 16));
    int b = rowptr[v], e = rowptr[v + 1];
    int i = b;
    for (; i + 8 <= e; i += 8) {
        int idx[8]; uint_t x[8];
#pragma unroll
        for (int k = 0; k < 8; ++k) idx[k] = esrc[i + k];
#pragma unroll
        for (int k = 0; k < 8; ++k) x[k] = th2[(size_t)idx[k] * 64 + lane];
#pragma unroll
        for (int k = 0; k < 8; ++k) {
            sx[k] += h2f((ushort_t)(x[k] & 0xFFFFu));
            sy[k] += h2f((ushort_t)(x[k] >> 16));
        }
    }
    for (; i < e; ++i) {
        uint_t x = th2[(size_t)esrc[i] * 64 + lane];
        sx[0] += h2f((ushort_t)(x & 0xFFFFu)); sy[0] += h2f((ushort_t)(x >> 16));
    }
    float fx = ((sx[0] + sx[1]) + (sx[2] + sx[3])) + ((sx[4] + sx[5]) + (sx[6] + sx[7]));
    float fy = ((sy[0] + sy[1]) + (sy[2] + sy[3])) + ((sy[4] + sy[5]) + (sy[6] + sy[7]));
    float2 A = *(const float2*)&bnA0[lane * 2];
    float2 B = *(const float2*)&bnB0[lane * 2];
    float cf = (float)(e - b + 1);
    float ox = A.x * fx + cf * B.x;
    float oy = A.y * fy + cf * B.y;
    aggb2[(size_t)v * 64 + lane] = (uint_t)f2h(ox) | ((uint_t)f2h(oy) << 16);
}

// last-block BN reduction shared by k_gin/k_ffn epilogues:
// producer blocks wrote partS/partQ rows; the last arriving block reduces them
// into per-channel affine (bnA,bnB). Device-scope release/acquire per G16.
__device__ __forceinline__ void bn_lastblock(int tid, float* sS, float* sQ,
                                             const float* __restrict__ partS,
                                             const float* __restrict__ partQ,
                                             const float* __restrict__ g,
                                             const float* __restrict__ b,
                                             float* __restrict__ bnA,
                                             float* __restrict__ bnB,
                                             int* __restrict__ ctr) {
    __threadfence();                       // release this block's partial writes
    __shared__ int isLast;
    if (tid == 0) {
        int old = __hip_atomic_fetch_add(ctr, 1, __ATOMIC_ACQ_REL, __HIP_MEMORY_SCOPE_AGENT);
        isLast = (old == NBM - 1);
    }
    __syncthreads();
    if (!isLast) return;
    float s = 0.f;
    const float* src = (tid < 128) ? (partS + (size_t)tid * NBM)
                                   : (partQ + (size_t)(tid - 128) * NBM);
    for (int i = 0; i < NBM; ++i) s += src[i];
    if (tid < 128) sS[tid] = s; else sQ[tid - 128] = s;
    __syncthreads();
    if (tid < 128) {
        float mu = sS[tid] * (1.0f / NN);
        float var = sQ[tid] * (1.0f / NN) - mu * mu;
        float inv = rsqrtf(var + BNEPS);
        float a = g[tid] * inv;
        bnA[tid] = a;
        bnB[tid] = b[tid] - mu * a;
    }
}

// ---------------- fused GIN MLP (256 threads, 32-row strips):
// z2 = (relu(agg@W1+b1))@W2+b2, z1 stays in LDS.
// r11: 512-thr variant halves MFMA-per-ds_read -> regressed.
// r12: register-prefetch of W chunks raises VGPR/spills -> regressed.
// This plain 2-barrier-per-chunk shape is the measured optimum of the family.
// BN-param reduction folded in via last-block (saves a separate launch). ----------------
#define GLDK 136
__global__ __launch_bounds__(256)
void k_gin(const ushort_t* __restrict__ A, const ushort_t* __restrict__ W1T,
           const ushort_t* __restrict__ W2T, const float* __restrict__ b1,
           const float* __restrict__ b2, ushort_t* __restrict__ z2h,
           float* __restrict__ partS, float* __restrict__ partQ,
           const float* __restrict__ gBN, const float* __restrict__ bBN,
           float* __restrict__ bnA1, float* __restrict__ bnB1,
           int* __restrict__ ctr) {
    __shared__ ushort_t As[128 * GLDK];   // A tile, later reused for z1 (A-layout)
    __shared__ ushort_t Ws[64 * GLDK];    // weight chunk (64 output-cols x K=128)
    __shared__ float sS[128], sQ[128];
    const int tid = threadIdx.x;
    const int w = tid >> 6, l = tid & 63;
    const int lm = l & 15, lq = l >> 4;
    const int rw0 = w * 32;               // wave's 32-row strip
    const int vr0 = blockIdx.x * 128;
    if (tid < 128) { sS[tid] = 0.f; sQ[tid] = 0.f; }

    // stage A tile (K=128 all at once)
#pragma unroll
    for (int it = 0; it < 8; ++it) {
        int f = it * 256 + tid;           // 2048 16B slots
        int row = f >> 4, sl = f & 15;
        uint4 a = make_uint4(0, 0, 0, 0);
        int vr = vr0 + row;
        if (vr < NN) a = *(const uint4*)&A[(size_t)vr * HD + sl * 8];
        *(uint4*)&As[row * GLDK + sl * 8] = a;
    }

    // phase 1: z1 = A @ W1 (col chunks of 64)
    f32x4 z1a[2][2][4] = {};
    for (int c = 0; c < 2; ++c) {
        __syncthreads();
#pragma unroll
        for (int it = 0; it < 4; ++it) {
            int f = it * 256 + tid;
            int row = f >> 4, sl = f & 15;
            *(uint4*)&Ws[row * GLDK + sl * 8] =
                *(const uint4*)&W1T[(size_t)(c * 64 + row) * HD + sl * 8];
        }
        __syncthreads();
#pragma unroll
        for (int kk = 0; kk < 128; kk += 32) {
            f16x8 af[2], bf[4];
#pragma unroll
            for (int i = 0; i < 2; ++i)
                af[i] = *(const f16x8*)&As[(rw0 + i * 16 + lm) * GLDK + kk + lq * 8];
#pragma unroll
            for (int j = 0; j < 4; ++j)
                bf[j] = *(const f16x8*)&Ws[(j * 16 + lm) * GLDK + kk + lq * 8];
#pragma unroll
            for (int i = 0; i < 2; ++i)
#pragma unroll
                for (int j = 0; j < 4; ++j)
                    z1a[c][i][j] = __builtin_amdgcn_mfma_f32_16x16x32_f16(af[i], bf[j], z1a[c][i][j], 0, 0, 0);
        }
    }
    __syncthreads();                       // all A reads done; safe to overwrite with z1

    // write z1 = relu(z1a + b1) back into As in A-fragment layout (wave-private rows)
#pragma unroll
    for (int c = 0; c < 2; ++c)
#pragma unroll
        for (int j = 0; j < 4; ++j) {
            int col = c * 64 + j * 16 + lm;
            float bj = b1[col];
#pragma unroll
            for (int r = 0; r < 4; ++r) {
                int row0_ = rw0 + lq * 4 + r;
                As[row0_ * GLDK + col] = f2h(fmaxf(z1a[c][0][j][r] + bj, 0.f));
                As[(row0_ + 16) * GLDK + col] = f2h(fmaxf(z1a[c][1][j][r] + bj, 0.f));
            }
        }

    // phase 2: z2 = z1 @ W2
    f32x4 z2a[2][2][4] = {};
    for (int c2 = 0; c2 < 2; ++c2) {
        __syncthreads();
#pragma unroll
        for (int it = 0; it < 4; ++it) {
            int f = it * 256 + tid;
            int row = f >> 4, sl = f & 15;
            *(uint4*)&Ws[row * GLDK + sl * 8] =
                *(const uint4*)&W2T[(size_t)(c2 * 64 + row) * HD + sl * 8];
        }
        __syncthreads();
#pragma unroll
        for (int kk = 0; kk < 128; kk += 32) {
            f16x8 af[2], bf[4];
#pragma unroll
            for (int i = 0; i < 2; ++i)
                af[i] = *(const f16x8*)&As[(rw0 + i * 16 + lm) * GLDK + kk + lq * 8];
#pragma unroll
            for (int j = 0; j < 4; ++j)
                bf[j] = *(const f16x8*)&Ws[(j * 16 + lm) * GLDK + kk + lq * 8];
#pragma unroll
            for (int i = 0; i < 2; ++i)
#pragma unroll
                for (int j = 0; j < 4; ++j)
                    z2a[c2][i][j] = __builtin_amdgcn_mfma_f32_16x16x32_f16(af[i], bf[j], z2a[c2][i][j], 0, 0, 0);
        }
    }

    // epilogue: bias + fp16 store + BN partial stats
    float ls[2][4] = {}, lsq[2][4] = {};
#pragma unroll
    for (int c2 = 0; c2 < 2; ++c2)
#pragma unroll
        for (int j = 0; j < 4; ++j) {
            int col = c2 * 64 + j * 16 + lm;
            float bj = b2[col];
#pragma unroll
            for (int i = 0; i < 2; ++i)
#pragma unroll
                for (int r = 0; r < 4; ++r) {
                    int vr = vr0 + rw0 + i * 16 + lq * 4 + r;
                    if (vr < NN) {
                        float x = z2a[c2][i][j][r] + bj;
                        ls[c2][j] += x; lsq[c2][j] += x * x;
                        z2h[(size_t)vr * HD + col] = f2h(x);
                    }
                }
        }
#pragma unroll
    for (int c2 = 0; c2 < 2; ++c2)
#pragma unroll
        for (int j = 0; j < 4; ++j) {
            atomicAdd(&sS[c2 * 64 + j * 16 + lm], ls[c2][j]);
            atomicAdd(&sQ[c2 * 64 + j * 16 + lm], lsq[c2][j]);
        }
    __syncthreads();
    if (tid < 128) {
        partS[(size_t)tid * NBM + blockIdx.x] = sS[tid];
        partQ[(size_t)tid * NBM + blockIdx.x] = sQ[tid];
    }
    __syncthreads();
    bn_lastblock(tid, sS, sQ, partS, partQ, gBN, bBN, bnA1, bnB1, ctr);
}

// ---------------- fused FFN (256 threads, 32-row strips):
// h_mid = (A0∘t+B0) + relu(A1∘z2+B1) staged in LDS; f1 kept in LDS per 64-col
// chunk (never hits HBM); t_new = f1@W4 + b4 + h_mid. Fs rows are wave-private.
// BN-param reduction for the NEXT layer folded in via last-block. ----------------
#define FLDK 72
__global__ __launch_bounds__(256)
void k_ffn(ushort_t* __restrict__ th, const ushort_t* __restrict__ z2h,
           const ushort_t* __restrict__ W3T, const float* __restrict__ b3,
           const ushort_t* __restrict__ W4T, const float* __restrict__ b4,
           const float* __restrict__ bnA0, const float* __restrict__ bnB0,
           const float* __restrict__ bnA1, const float* __restrict__ bnB1,
           float* __restrict__ partS, float* __restrict__ partQ,
           const float* __restrict__ gBN, const float* __restrict__ bBN,
           float* __restrict__ obnA, float* __restrict__ obnB,
           int* __restrict__ ctr) {
    __shared__ ushort_t As[128 * GLDK];   // h_mid tile (A of GEMM1 + residual source)
    __shared__ ushort_t Fs[128 * FLDK];   // f1 chunk (A of GEMM2), wave-private rows
    __shared__ ushort_t Ws[128 * FLDK];   // W3 chunk (64x128 @GLDK) or W4 chunk (128x64 @FLDK)
    __shared__ float sS[128], sQ[128];
    __shared__ float sA0[128], sB0[128], sA1[128], sB1[128];
    const int tid = threadIdx.x;
    const int w = tid >> 6, l = tid & 63;
    const int lm = l & 15, lq = l >> 4;
    const int rw0 = w * 32;
    const int vr0 = blockIdx.x * 128;

    if (tid < 128) {
        sS[tid] = 0.f; sQ[tid] = 0.f;
        sA0[tid] = bnA0[tid]; sB0[tid] = bnB0[tid];
        sA1[tid] = bnA1[tid]; sB1[tid] = bnB1[tid];
    }
    __syncthreads();

    // stage h_mid into As (fp16)
#pragma unroll
    for (int it = 0; it < 8; ++it) {
        int f = it * 256 + tid;           // 2048 16B slots
        int row = f >> 4, sl = f & 15;
        int vr = vr0 + row;
        uint4 o = make_uint4(0, 0, 0, 0);
        if (vr < NN) {
            uint4 tv = *(const uint4*)&th[(size_t)vr * HD + sl * 8];
            uint4 zv = *(const uint4*)&z2h[(size_t)vr * HD + sl * 8];
            uint_t tu[4] = {tv.x, tv.y, tv.z, tv.w};
            uint_t zu[4] = {zv.x, zv.y, zv.z, zv.w};
            uint_t ou[4];
#pragma unroll
            for (int m = 0; m < 4; ++m) {
                int ch0 = sl * 8 + m * 2;
                float t0 = h2f((ushort_t)(tu[m] & 0xFFFFu));
                float t1 = h2f((ushort_t)(tu[m] >> 16));
                float z0 = h2f((ushort_t)(zu[m] & 0xFFFFu));
                float z1 = h2f((ushort_t)(zu[m] >> 16));
                float h0 = sA0[ch0] * t0 + sB0[ch0] + fmaxf(sA1[ch0] * z0 + sB1[ch0], 0.f);
                float h1 = sA0[ch0 + 1] * t1 + sB0[ch0 + 1] + fmaxf(sA1[ch0 + 1] * z1 + sB1[ch0 + 1], 0.f);
                ou[m] = (uint_t)f2h(h0) | ((uint_t)f2h(h1) << 16);
            }
            o = make_uint4(ou[0], ou[1], ou[2], ou[3]);
        }
        *(uint4*)&As[row * GLDK + sl * 8] = o;
    }

    f32x4 acc2[2][2][4] = {};   // ffn2 acc: [out-col-chunk][row frag][col frag]
    for (int kc = 0; kc < 4; ++kc) {
        // ---- GEMM1: f1_kc = relu(h_mid @ W3[:, kc*64..+64) + b3) into Fs ----
        __syncthreads();                   // prior Ws readers done (and As staged, 1st iter)
#pragma unroll
        for (int it = 0; it < 4; ++it) {
            int f = it * 256 + tid;
            int row = f >> 4, sl = f & 15; // 64 rows x 128 k
            *(uint4*)&Ws[row * GLDK + sl * 8] =
                *(const uint4*)&W3T[(size_t)(kc * 64 + row) * HD + sl * 8];
        }
        __syncthreads();
        f32x4 f1a[2][4] = {};
#pragma unroll
        for (int kk = 0; kk < 128; kk += 32) {
            f16x8 af[2], bf[4];
#pragma unroll
            for (int i = 0; i < 2; ++i)
                af[i] = *(const f16x8*)&As[(rw0 + i * 16 + lm) * GLDK + kk + lq * 8];
#pragma unroll
            for (int j = 0; j < 4; ++j)
                bf[j] = *(const f16x8*)&Ws[(j * 16 + lm) * GLDK + kk + lq * 8];
#pragma unroll
            for (int i = 0; i < 2; ++i)
#pragma unroll
                for (int j = 0; j < 4; ++j)
                    f1a[i][j] = __builtin_amdgcn_mfma_f32_16x16x32_f16(af[i], bf[j], f1a[i][j], 0, 0, 0);
        }
        // write relu(f1+b3) into Fs in A-fragment layout (wave-private rows)
#pragma unroll
        for (int j = 0; j < 4; ++j) {
            int fcol = j * 16 + lm;
            float bj = b3[kc * 64 + fcol];
#pragma unroll
            for (int r = 0; r < 4; ++r) {
                int row0_ = rw0 + lq * 4 + r;
                Fs[row0_ * FLDK + fcol] = f2h(fmaxf(f1a[0][j][r] + bj, 0.f));
                Fs[(row0_ + 16) * FLDK + fcol] = f2h(fmaxf(f1a[1][j][r] + bj, 0.f));
            }
        }
        // ---- GEMM2 partial: acc2 += Fs @ W4[kc*64..+64, :] ----
        __syncthreads();                   // all waves done reading Ws (W3)
#pragma unroll
        for (int it = 0; it < 4; ++it) {
            int f = it * 256 + tid;
            int row = f >> 3, sl = f & 7;  // 128 out-cols x 64 k
            *(uint4*)&Ws[row * FLDK + sl * 8] =
                *(const uint4*)&W4T[(size_t)row * 256 + kc * 64 + sl * 8];
        }
        __syncthreads();
#pragma unroll
        for (int kk = 0; kk < 64; kk += 32) {
            f16x8 af[2];
#pragma unroll
            for (int i = 0; i < 2; ++i)
                af[i] = *(const f16x8*)&Fs[(rw0 + i * 16 + lm) * FLDK + kk + lq * 8];
#pragma unroll
            for (int c2 = 0; c2 < 2; ++c2)
#pragma unroll
                for (int j = 0; j < 4; ++j) {
                    f16x8 bf = *(const f16x8*)&Ws[(c2 * 64 + j * 16 + lm) * FLDK + kk + lq * 8];
#pragma unroll
                    for (int i = 0; i < 2; ++i)
                        acc2[c2][i][j] = __builtin_amdgcn_mfma_f32_16x16x32_f16(af[i], bf, acc2[c2][i][j], 0, 0, 0);
                }
        }
    }

    // epilogue: x = acc2 + b4 + h_mid(LDS fp16); write th + BN partial stats
    float ls[2][4] = {}, lsq[2][4] = {};
#pragma unroll
    for (int c2 = 0; c2 < 2; ++c2)
#pragma unroll
        for (int j = 0; j < 4; ++j) {
            int col = c2 * 64 + j * 16 + lm;
            float bj = b4[col];
#pragma unroll
            for (int i = 0; i < 2; ++i)
#pragma unroll
                for (int r = 0; r < 4; ++r) {
                    int lrow = rw0 + i * 16 + lq * 4 + r;
                    int vr = vr0 + lrow;
                    if (vr < NN) {
                        float resv = h2f(As[lrow * GLDK + col]);
                        float x = acc2[c2][i][j][r] + bj + resv;
                        ls[c2][j] += x; lsq[c2][j] += x * x;
                        th[(size_t)vr * HD + col] = f2h(x);
                    }
                }
        }
#pragma unroll
    for (int c2 = 0; c2 < 2; ++c2)
#pragma unroll
        for (int j = 0; j < 4; ++j) {
            atomicAdd(&sS[c2 * 64 + j * 16 + lm], ls[c2][j]);
            atomicAdd(&sQ[c2 * 64 + j * 16 + lm], lsq[c2][j]);
        }
    __syncthreads();
    if (tid < 128) {
        partS[(size_t)tid * NBM + blockIdx.x] = sS[tid];
        partQ[(size_t)tid * NBM + blockIdx.x] = sQ[tid];
    }
    __syncthreads();
    bn_lastblock(tid, sS, sQ, partS, partQ, gBN, bBN, obnA, obnB, ctr);
}

// pooling over raw th: gsum[g] = sum_v t[v]; affine applied in k_head
__global__ void k_pool(const uint2* __restrict__ th4, const int* __restrict__ goff,
                       const int* __restrict__ cnt, float* __restrict__ gsum) {
    __shared__ float4 sm[256];
    int g = blockIdx.x >> 2, sub = blockIdx.x & 3;
    int n0 = goff[g], n = cnt[g];
    int cg = threadIdx.x & 31, rl = threadIdx.x >> 5;  // rl 0..7
    float4 acc = make_float4(0.f, 0.f, 0.f, 0.f);
    for (int r = sub * 8 + rl; r < n; r += 32) {
        uint2 v = th4[(size_t)(n0 + r) * 32 + cg];
        acc.x += h2f((ushort_t)(v.x & 0xFFFFu));
        acc.y += h2f((ushort_t)(v.x >> 16));
        acc.z += h2f((ushort_t)(v.y & 0xFFFFu));
        acc.w += h2f((ushort_t)(v.y >> 16));
    }
    sm[threadIdx.x] = acc; __syncthreads();
    for (int st = 128; st >= 32; st >>= 1) {
        if (threadIdx.x < st) {
            float4 o = sm[threadIdx.x + st];
            sm[threadIdx.x].x += o.x; sm[threadIdx.x].y += o.y;
            sm[threadIdx.x].z += o.z; sm[threadIdx.x].w += o.w;
        }
        __syncthreads();
    }
    if (threadIdx.x < 32) {
        float4 v = sm[threadIdx.x];
        atomicAdd(&gsum[g * HD + cg * 4 + 0], v.x);
        atomicAdd(&gsum[g * HD + cg * 4 + 1], v.y);
        atomicAdd(&gsum[g * HD + cg * 4 + 2], v.z);
        atomicAdd(&gsum[g * HD + cg * 4 + 3], v.w);
    }
}

__global__ void k_head(const float* __restrict__ gsum, const int* __restrict__ cnt,
                       const float* __restrict__ bnA0, const float* __restrict__ bnB0,
                       const float* __restrict__ w1, const float* __restrict__ b1,
                       const float* __restrict__ w2, const float* __restrict__ b2,
                       float* __restrict__ out) {
    __shared__ float gv[HD], av[HD];
    int gid = blockIdx.x, t = threadIdx.x;
    float c = fmaxf((float)cnt[gid], 1.0f);
    gv[t] = bnA0[t] * (gsum[gid * HD + t] / c) + bnB0[t];   // mean then affine
    __syncthreads();
    float a = b1[t];
    for (int k = 0; k < HD; ++k) a += gv[k] * w1[k * HD + t];
    av[t] = fmaxf(a, 0.f);
    __syncthreads();
    if (t < NOUT) {
        float o = b2[t];
        for (int k = 0; k < HD; ++k) o += av[k] * w2[k * NOUT + t];
        out[gid * NOUT + t] = o;
    }
}

// ---------------- workspace layout ----------------
// z2h keeps a DEDICATED region (round-6 race lesson). aggh/epair share one
// arena. Sync counters live in the zeroed arena (memset each call).
static constexpr size_t AL(size_t x) { return (x + 511) & ~(size_t)511; }
static constexpr size_t OFF_TH     = 0;                                         // fp16 t (BN input)
static constexpr size_t OFF_SHARE  = OFF_TH     + AL((size_t)NN * HD * 2);
static constexpr size_t SZ_SHARE   = AL((size_t)NN * HD * 2);                   // aggh | epair
static constexpr size_t OFF_Z2     = OFF_SHARE  + SZ_SHARE;                     // z2h fp16 (dedicated)
static constexpr size_t OFF_RW     = OFF_Z2     + AL((size_t)NN * HD * 2);
static constexpr size_t OFF_P0     = OFF_RW     + AL((size_t)WLK * NN * 4);
static constexpr size_t OFF_P1     = OFF_P0     + AL((size_t)NN * 4);
static constexpr size_t OFF_PD0    = OFF_P1     + AL((size_t)NN * 4);
static constexpr size_t OFF_PD1    = OFF_PD0    + AL((size_t)NN * 4);
static constexpr size_t OFF_DINV   = OFF_PD1    + AL((size_t)NN * 4);
static constexpr size_t OFF_ESRC   = OFF_DINV   + AL((size_t)NN * 4);
static constexpr size_t OFF_ROWPTR = OFF_ESRC   + AL((size_t)NE * 4);
static constexpr size_t OFF_DEG    = OFF_ROWPTR + AL((size_t)(NN + 1) * 4);
static constexpr size_t OFF_BHIST  = OFF_DEG    + AL((size_t)NN * 4);
static constexpr size_t OFF_BOFFS  = OFF_BHIST  + AL((size_t)NSCAN * 4);
static constexpr size_t OFF_BSUM   = OFF_BOFFS  + AL((size_t)NSCAN * 4);
static constexpr size_t OFF_WT1    = OFF_BSUM   + AL(512 * 4);
static constexpr size_t OFF_WT2    = OFF_WT1    + AL((size_t)5 * 16384 * 2);
static constexpr size_t OFF_WT3    = OFF_WT2    + AL((size_t)5 * 16384 * 2);
static constexpr size_t OFF_WT4    = OFF_WT3    + AL((size_t)5 * 32768 * 2);
static constexpr size_t OFF_PARTS  = OFF_WT4    + AL((size_t)5 * 32768 * 2);
static constexpr size_t OFF_PARTQ  = OFF_PARTS  + AL((size_t)128 * NBM * 4);
static constexpr size_t OFF_BNA0   = OFF_PARTQ  + AL((size_t)128 * NBM * 4);
static constexpr size_t OFF_BNB0   = OFF_BNA0   + AL(128 * 4);
static constexpr size_t OFF_BNA1   = OFF_BNB0   + AL(128 * 4);
static constexpr size_t OFF_BNB1   = OFF_BNA1   + AL(128 * 4);
static constexpr size_t OFF_M      = OFF_BNB1   + AL(128 * 4);
static constexpr size_t OFF_C1     = OFF_M      + AL((size_t)WLK * HD * 4);
static constexpr size_t OFF_CNT    = OFF_C1     + AL(HD * 4);
static constexpr size_t OFF_GOFF   = OFF_CNT    + AL(NG * 4);
// zero arena: gsum + sync counters (10 BN + 16 rw)
static constexpr size_t OFF_GSUM   = OFF_GOFF   + AL(NG * 4);
static constexpr size_t OFF_CTR    = OFF_GSUM   + AL((size_t)NG * HD * 4);
static constexpr size_t ZERO_BYTES = (OFF_CTR - OFF_GSUM) + 26 * 4;

extern "C" void kernel_launch(void* const* d_in, const int* in_sizes, int n_in,
                              void* d_out, int out_size, void* d_ws, size_t ws_size,
                              hipStream_t stream) {
    const int* eidx = (const int*)d_in[1];
    const int* row0 = eidx;
    const int* col0 = eidx + NE;
    const int* batch = (const int*)d_in[2];
    const float* emb = (const float*)d_in[3];
    const float* pe_w = (const float*)d_in[4];
    const float* pe_b = (const float*)d_in[5];
    const float* proj_w = (const float*)d_in[6];
    const float* proj_b = (const float*)d_in[7];
    const float* gin_w1 = (const float*)d_in[8];
    const float* gin_b1 = (const float*)d_in[9];
    const float* gin_w2 = (const float*)d_in[10];
    const float* gin_b2 = (const float*)d_in[11];
    const float* bn_g = (const float*)d_in[12];
    const float* bn_b = (const float*)d_in[13];
    const float* ffn_w1 = (const float*)d_in[14];
    const float* ffn_b1 = (const float*)d_in[15];
    const float* ffn_w2 = (const float*)d_in[16];
    const float* ffn_b2 = (const float*)d_in[17];
    const float* ffn_bn_g = (const float*)d_in[18];
    const float* ffn_bn_b = (const float*)d_in[19];
    const float* out_w1 = (const float*)d_in[20];
    const float* out_b1 = (const float*)d_in[21];
    const float* out_w2 = (const float*)d_in[22];
    const float* out_b2 = (const float*)d_in[23];
    float* out = (float*)d_out;

    char* ws = (char*)d_ws;
    ushort_t* th    = (ushort_t*)(ws + OFF_TH);
    ushort_t* aggh  = (ushort_t*)(ws + OFF_SHARE);
    int2*     epair = (int2*)(ws + OFF_SHARE);
    ushort_t* z2h   = (ushort_t*)(ws + OFF_Z2);
    float*    rw    = (float*)(ws + OFF_RW);
    float*    p0    = (float*)(ws + OFF_P0);
    float*    p1    = (float*)(ws + OFF_P1);
    float*    pd0   = (float*)(ws + OFF_PD0);
    float*    pd1   = (float*)(ws + OFF_PD1);
    float*    dinv  = (float*)(ws + OFF_DINV);
    int*      esrc  = (int*)(ws + OFF_ESRC);
    int*      rowptr= (int*)(ws + OFF_ROWPTR);
    int*      deg   = (int*)(ws + OFF_DEG);
    int*      bhist = (int*)(ws + OFF_BHIST);
    int*      boffs = (int*)(ws + OFF_BOFFS);
    int*      bsum  = (int*)(ws + OFF_BSUM);
    ushort_t* wt1   = (ushort_t*)(ws + OFF_WT1);
    ushort_t* wt2   = (ushort_t*)(ws + OFF_WT2);
    ushort_t* wt3   = (ushort_t*)(ws + OFF_WT3);
    ushort_t* wt4   = (ushort_t*)(ws + OFF_WT4);
    float*    partS = (float*)(ws + OFF_PARTS);
    float*    partQ = (float*)(ws + OFF_PARTQ);
    float*    bnA0  = (float*)(ws + OFF_BNA0);
    float*    bnB0  = (float*)(ws + OFF_BNB0);
    float*    bnA1  = (float*)(ws + OFF_BNA1);
    float*    bnB1  = (float*)(ws + OFF_BNB1);
    float*    M     = (float*)(ws + OFF_M);
    float*    c1    = (float*)(ws + OFF_C1);
    int*      cnt   = (int*)(ws + OFF_CNT);
    int*      goff  = (int*)(ws + OFF_GOFF);
    float*    gsum  = (float*)(ws + OFF_GSUM);
    int*      sctr  = (int*)(ws + OFF_CTR);   // [0..9] BN folds, [10..25] rw barriers

    const int NB = CDIV(NN, 256);        // 391
    const int NBV = CDIV(NN * 32, 256);  // 12500

    hipMemsetAsync(ws + OFF_GSUM, 0, ZERO_BYTES, stream);

    // ---- atomic-free CSR build ----
    k_cnt<<<1, 128, 0, stream>>>(batch, cnt, goff);
    k_bhist<<<NEB, 256, 0, stream>>>(col0, bhist);
    k_gscan1<<<NSB, 256, 0, stream>>>(bhist, bsum);
    k_scan2<<<1, 512, 0, stream>>>(bsum, NSB);
    k_gscan3<<<NSB, 256, 0, stream>>>(bhist, bsum, boffs);
    k_escatter<<<NEB, 256, 0, stream>>>(row0, col0, boffs, epair);
    k_bucket<<<NBKT, 256, 0, stream>>>(epair, boffs, rowptr, deg, esrc);

    // ---- PE + projection ----
    k_init_pe<<<NB, 256, 0, stream>>>(deg, batch, cnt, dinv, p0, pd0);
    k_mc1<<<1, 128, 0, stream>>>(emb, pe_w, pe_b, proj_w, proj_b, M, c1, bnA0, bnB0);
    k_prepw<<<1920, 256, 0, stream>>>(gin_w1, gin_w2, ffn_w1, ffn_w2, wt1, wt2, wt3, wt4);
    k_rw_all<<<NBRW, 256, 0, stream>>>(p0, p1, pd0, pd1, rowptr, esrc, dinv, rw, sctr + 10);
    k_proj<<<NBV, 256, 0, stream>>>(rw, M, c1, (uint2*)th);

    // ---- layers: gather | GIN-MLP(+BN fold) | fused-FFN(+BN fold) ----
    for (int i = 0; i < NL; ++i) {
        k_aggb<<<CDIV(NN, 4), 256, 0, stream>>>((const uint_t*)th, rowptr, esrc,
                                                bnA0, bnB0, (uint_t*)aggh);
        k_gin<<<NBM, 256, 0, stream>>>(aggh, wt1 + (size_t)i * 16384, wt2 + (size_t)i * 16384,
                                       gin_b1 + i * HD, gin_b2 + i * HD, z2h, partS, partQ,
                                       bn_g + i * HD, bn_b + i * HD, bnA1, bnB1, sctr + i);
        k_ffn<<<NBM, 256, 0, stream>>>(th, z2h, wt3 + (size_t)i * 32768, ffn_b1 + i * 256,
                                       wt4 + (size_t)i * 32768, ffn_b2 + i * HD,
                                       bnA0, bnB0, bnA1, bnB1, partS, partQ,
                                       ffn_bn_g + i * HD, ffn_bn_b + i * HD, bnA0, bnB0,
                                       sctr + 5 + i);
    }

    k_pool<<<NG * 4, 256, 0, stream>>>((const uint2*)th, goff, cnt, gsum);
    k_head<<<NG, 128, 0, stream>>>(gsum, cnt, bnA0, bnB0, out_w1, out_b1, out_w2, out_b2, out);
}

// Round 15
// 1433.325 us; speedup vs baseline: 2.8957x; 2.8957x over previous
//
#include <hip/hip_runtime.h>
#include <math.h>

#define NN 100000
#define NE 1600000
#define NG 128
#define HD 128
#define WLK 16
#define NL 5
#define NOUT 10
#define BNEPS 1e-5f
#define CDIV(a,b) (((a)+(b)-1)/(b))

#define NBKT 782          // buckets of 128 nodes (col>>7)
#define NEB 400           // edge-blocks for bucketing
#define EPB 4000          // edges per edge-block (NEB*EPB == NE)
#define NSCAN (NBKT*NEB)  // 312800
#define NSB CDIV(NSCAN,1024)  // 306
#define NBM 782           // GEMM row-blocks (CDIV(NN,128))

typedef float f32x4 __attribute__((ext_vector_type(4)));
typedef _Float16 f16x8 __attribute__((ext_vector_type(8)));
typedef unsigned short ushort_t;
typedef unsigned int uint_t;

__device__ __forceinline__ ushort_t f2h(float x) {
    union { _Float16 h; ushort_t u; } c;
    c.h = (_Float16)x;                     // v_cvt_f16_f32, RNE
    return c.u;
}
__device__ __forceinline__ float h2f(ushort_t u) {
    union { ushort_t u; _Float16 h; } c;
    c.u = u;
    return (float)c.h;
}

// ---------------- graph counts + start offsets via binary search (batch sorted) ----------------
__global__ void k_cnt(const int* __restrict__ batch, int* __restrict__ cnt,
                      int* __restrict__ goff) {
    int g = threadIdx.x;
    if (g >= NG) return;
    int lo0 = 0, hi0 = NN;
    while (lo0 < hi0) { int m = (lo0 + hi0) >> 1; if (batch[m] < g) lo0 = m + 1; else hi0 = m; }
    int lo1 = lo0, hi1 = NN;
    while (lo1 < hi1) { int m = (lo1 + hi1) >> 1; if (batch[m] < g + 1) lo1 = m + 1; else hi1 = m; }
    cnt[g] = lo1 - lo0;
    goff[g] = lo0;
}

// ---------------- atomic-free CSR build: bucket histogram ----------------
__global__ void k_bhist(const int* __restrict__ col0, int* __restrict__ bhist) {
    __shared__ int hist[NBKT];
    for (int i = threadIdx.x; i < NBKT; i += 256) hist[i] = 0;
    __syncthreads();
    int e0 = blockIdx.x * EPB;
    for (int e = e0 + threadIdx.x; e < e0 + EPB; e += 256) atomicAdd(&hist[col0[e] >> 7], 1);
    __syncthreads();
    for (int i = threadIdx.x; i < NBKT; i += 256) bhist[i * NEB + blockIdx.x] = hist[i];
}

__global__ void k_gscan1(const int* __restrict__ in, int* __restrict__ bsum) {
    __shared__ int sm[256];
    int base = blockIdx.x * 1024 + threadIdx.x * 4;
    int s = 0;
#pragma unroll
    for (int i = 0; i < 4; ++i) { int e = base + i; if (e < NSCAN) s += in[e]; }
    sm[threadIdx.x] = s; __syncthreads();
    for (int st = 128; st > 0; st >>= 1) {
        if (threadIdx.x < st) sm[threadIdx.x] += sm[threadIdx.x + st];
        __syncthreads();
    }
    if (threadIdx.x == 0) bsum[blockIdx.x] = sm[0];
}

__global__ void k_scan2(int* __restrict__ blksum, int nblk) {
    __shared__ int sm[512];
    int t = threadIdx.x;
    int x = (t < nblk) ? blksum[t] : 0;
    sm[t] = x; __syncthreads();
    for (int s = 1; s < 512; s <<= 1) {
        int v = (t >= s) ? sm[t - s] : 0;
        __syncthreads();
        sm[t] += v;
        __syncthreads();
    }
    if (t < nblk) blksum[t] = sm[t] - x;   // exclusive
}

__global__ void k_gscan3(const int* __restrict__ in, const int* __restrict__ bsum,
                         int* __restrict__ out) {
    __shared__ int sm[256];
    int t = threadIdx.x;
    int base = blockIdx.x * 1024 + t * 4;
    int v[4]; int s = 0;
#pragma unroll
    for (int i = 0; i < 4; ++i) { int e = base + i; v[i] = (e < NSCAN) ? in[e] : 0; s += v[i]; }
    sm[t] = s; __syncthreads();
    for (int st = 1; st < 256; st <<= 1) {
        int x = (t >= st) ? sm[t - st] : 0;
        __syncthreads();
        sm[t] += x;
        __syncthreads();
    }
    int excl = sm[t] - s + bsum[blockIdx.x];
#pragma unroll
    for (int i = 0; i < 4; ++i) { int e = base + i; if (e < NSCAN) { out[e] = excl; excl += v[i]; } }
}

__global__ void k_escatter(const int* __restrict__ row0, const int* __restrict__ col0,
                           const int* __restrict__ boffs, int2* __restrict__ epair) {
    __shared__ int cur[NBKT];
    for (int i = threadIdx.x; i < NBKT; i += 256) cur[i] = boffs[i * NEB + blockIdx.x];
    __syncthreads();
    int e0 = blockIdx.x * EPB;
    for (int e = e0 + threadIdx.x; e < e0 + EPB; e += 256) {
        int c = col0[e], r = row0[e];
        int pos = atomicAdd(&cur[c >> 7], 1);
        epair[pos] = make_int2(c, r);
    }
}

__global__ void k_bucket(const int2* __restrict__ epair, const int* __restrict__ boffs,
                         int* __restrict__ rowptr, int* __restrict__ deg,
                         int* __restrict__ esrc) {
    __shared__ int cnt_[128], scn[128], cur_[128];
    int bkt = blockIdx.x, t = threadIdx.x;
    int bs = boffs[bkt * NEB];
    int be = (bkt + 1 < NBKT) ? boffs[(bkt + 1) * NEB] : NE;
    if (t < 128) cnt_[t] = 0;
    __syncthreads();
    for (int e = bs + t; e < be; e += 256) atomicAdd(&cnt_[epair[e].x & 127], 1);
    __syncthreads();
    int c = (t < 128) ? cnt_[t] : 0;
    if (t < 128) scn[t] = c;
    __syncthreads();
    for (int st = 1; st < 128; st <<= 1) {
        int x = (t >= st && t < 128) ? scn[t - st] : 0;
        __syncthreads();
        if (t < 128) scn[t] += x;
        __syncthreads();
    }
    if (t < 128) {
        int excl = scn[t] - c;
        int node = bkt * 128 + t;
        if (node < NN) { rowptr[node] = bs + excl; deg[node] = c; }
        cur_[t] = bs + excl;
    }
    if (bkt == NBKT - 1 && t == 0) rowptr[NN] = NE;
    __syncthreads();
    for (int e = bs + t; e < be; e += 256) {
        int2 p = epair[e];
        int pos = atomicAdd(&cur_[p.x & 127], 1);
        esrc[pos] = p.y;
    }
}

// ---------------- PE init ----------------
__global__ void k_init_pe(const int* __restrict__ deg, const int* __restrict__ batch,
                          const int* __restrict__ cnt, float* __restrict__ dinv,
                          float* __restrict__ p, float* __restrict__ pd) {
    int v = blockIdx.x * 256 + threadIdx.x;
    if (v >= NN) return;
    float dv = rsqrtf((float)(deg[v] + 1));   // +1: self-loop
    dinv[v] = dv;
    float pv = 1.0f / fmaxf((float)cnt[batch[v]], 1.0f);
    p[v] = pv; pd[v] = pv * dv;
}

// one RW step; unroll-8 gathers for memory-level parallelism.
// r14 lesson: fusing all 16 steps into one kernel with a manual grid barrier
// was 15x SLOWER (1756us vs 112us) — agent-scope acquire/release fences per
// step wreck the caches; kernel boundaries provide the flush for free.
__global__ void k_rw_step(const float* __restrict__ pin, const float* __restrict__ pdin,
                          const int* __restrict__ rowptr, const int* __restrict__ esrc,
                          const float* __restrict__ dinv, float* __restrict__ rwslice,
                          float* __restrict__ pout, float* __restrict__ pdout) {
    int v = blockIdx.x * 256 + threadIdx.x;
    if (v >= NN) return;
    int b = rowptr[v], e = rowptr[v + 1];
    float a[8];
#pragma unroll
    for (int k = 0; k < 8; ++k) a[k] = 0.f;
    int i = b;
    for (; i + 8 <= e; i += 8) {
        int s[8];
#pragma unroll
        for (int k = 0; k < 8; ++k) s[k] = esrc[i + k];
#pragma unroll
        for (int k = 0; k < 8; ++k) a[k] += pdin[s[k]];
    }
    for (; i < e; ++i) a[0] += pdin[esrc[i]];
    float s = ((a[0] + a[1]) + (a[2] + a[3])) + ((a[4] + a[5]) + (a[6] + a[7]));
    float dv = dinv[v];
    float pv = pin[v];
    float np = s * dv + pv * dv * dv;
    float nxt = 0.9f * np + 0.1f * pv;
    rwslice[v] = pv;
    pout[v] = nxt;
    pdout[v] = nxt * dv;
}

// also initializes the identity affine for layer-0 (A0=1, B0=0)
__global__ void k_mc1(const float* __restrict__ emb, const float* __restrict__ pe_w,
                      const float* __restrict__ pe_b, const float* __restrict__ proj_w,
                      const float* __restrict__ proj_b, float* __restrict__ M,
                      float* __restrict__ c1, float* __restrict__ bnA0,
                      float* __restrict__ bnB0) {
    int j = threadIdx.x;
    bnA0[j] = 1.f; bnB0[j] = 0.f;
    float c0 = proj_b[j];
    for (int d = 0; d < HD; ++d) c0 += emb[d] * proj_w[d * HD + j];
    for (int w = 0; w < WLK; ++w) c0 += pe_b[w] * proj_w[(HD + w) * HD + j];
    c1[j] = c0;
    for (int s = 0; s < WLK; ++s) {
        float m = 0.f;
        for (int w = 0; w < WLK; ++w) m += pe_w[s * WLK + w] * proj_w[(HD + w) * HD + j];
        M[s * HD + j] = m;
    }
}

// th0[v][cg..cg+3] = fp16(c1 + sum_s rw[s][v]*M[s][:])
__global__ void k_proj(const float* __restrict__ rw, const float* __restrict__ M,
                       const float* __restrict__ c1, uint2* __restrict__ th4) {
    int idx = blockIdx.x * 256 + threadIdx.x;   // NN*32
    if (idx >= NN * 32) return;
    int v = idx >> 5, cg = (idx & 31) * 4;
    float4 acc = *(const float4*)&c1[cg];
#pragma unroll
    for (int s = 0; s < WLK; ++s) {
        float r = rw[s * NN + v];
        float4 m = *(const float4*)&M[s * HD + cg];
        acc.x += r * m.x; acc.y += r * m.y; acc.z += r * m.z; acc.w += r * m.w;
    }
    th4[idx] = make_uint2((uint_t)f2h(acc.x) | ((uint_t)f2h(acc.y) << 16),
                          (uint_t)f2h(acc.z) | ((uint_t)f2h(acc.w) << 16));
}

// cast + transpose all GEMM weights to fp16 [n][k] once per call
__global__ void k_prepw(const float* __restrict__ g1, const float* __restrict__ g2,
                        const float* __restrict__ f1, const float* __restrict__ f2,
                        ushort_t* __restrict__ wt1, ushort_t* __restrict__ wt2,
                        ushort_t* __restrict__ wt3, ushort_t* __restrict__ wt4) {
    int i = blockIdx.x * 256 + threadIdx.x;   // 491520 total
    if (i < 81920) {
        int l = i >> 14, rem = i & 16383, n = rem >> 7, k = rem & 127;
        wt1[i] = f2h(g1[l * 16384 + k * 128 + n]);
    } else if (i < 163840) {
        int j = i - 81920;
        int l = j >> 14, rem = j & 16383, n = rem >> 7, k = rem & 127;
        wt2[j] = f2h(g2[l * 16384 + k * 128 + n]);
    } else if (i < 327680) {
        int j = i - 163840;
        int l = j >> 15, rem = j & 32767, n = rem >> 7, k = rem & 127;
        wt3[j] = f2h(f1[l * 32768 + k * 256 + n]);
    } else {
        int j = i - 327680;
        int l = j >> 15, rem = j & 32767, n = rem >> 8, k = rem & 255;
        wt4[j] = f2h(f2[l * 32768 + k * 128 + n]);
    }
}

// agg[v] = A0∘(t[v] + sum_j t[src_j]) + (deg+1)∘B0  (standalone, high-occupancy:
// round-8 lesson — fusing this latency-bound gather into the LDS-heavy GEMM
// kernel cut occupancy 68%→19% and tripled its cost)
__global__ void k_aggb(const uint_t* __restrict__ th2, const int* __restrict__ rowptr,
                       const int* __restrict__ esrc, const float* __restrict__ bnA0,
                       const float* __restrict__ bnB0, uint_t* __restrict__ aggb2) {
    int wave = threadIdx.x >> 6, lane = threadIdx.x & 63;
    int v = blockIdx.x * 4 + wave;
    if (v >= NN) return;
    uint_t u = th2[(size_t)v * 64 + lane];
    float sx[8], sy[8];
#pragma unroll
    for (int k = 0; k < 8; ++k) { sx[k] = 0.f; sy[k] = 0.f; }
    sx[0] = h2f((ushort_t)(u & 0xFFFFu)); sy[0] = h2f((ushort_t)(u >> 16));
    int b = rowptr[v], e = rowptr[v + 1];
    int i = b;
    for (; i + 8 <= e; i += 8) {
        int idx[8]; uint_t x[8];
#pragma unroll
        for (int k = 0; k < 8; ++k) idx[k] = esrc[i + k];
#pragma unroll
        for (int k = 0; k < 8; ++k) x[k] = th2[(size_t)idx[k] * 64 + lane];
#pragma unroll
        for (int k = 0; k < 8; ++k) {
            sx[k] += h2f((ushort_t)(x[k] & 0xFFFFu));
            sy[k] += h2f((ushort_t)(x[k] >> 16));
        }
    }
    for (; i < e; ++i) {
        uint_t x = th2[(size_t)esrc[i] * 64 + lane];
        sx[0] += h2f((ushort_t)(x & 0xFFFFu)); sy[0] += h2f((ushort_t)(x >> 16));
    }
    float fx = ((sx[0] + sx[1]) + (sx[2] + sx[3])) + ((sx[4] + sx[5]) + (sx[6] + sx[7]));
    float fy = ((sy[0] + sy[1]) + (sy[2] + sy[3])) + ((sy[4] + sy[5]) + (sy[6] + sy[7]));
    float2 A = *(const float2*)&bnA0[lane * 2];
    float2 B = *(const float2*)&bnB0[lane * 2];
    float cf = (float)(e - b + 1);
    float ox = A.x * fx + cf * B.x;
    float oy = A.y * fy + cf * B.y;
    aggb2[(size_t)v * 64 + lane] = (uint_t)f2h(ox) | ((uint_t)f2h(oy) << 16);
}

// ---------------- fused GIN MLP (256 threads, 32-row strips):
// z2 = (relu(agg@W1+b1))@W2+b2, z1 stays in LDS.
// r11: 512-thr variant halves MFMA-per-ds_read -> regressed.
// r12: register-prefetch of W chunks raises VGPR/spills -> regressed.
// r14: BN-fold via last-block + device fences in all blocks -> regressed.
// This plain 2-barrier-per-chunk shape is the measured optimum of the family. ----------------
#define GLDK 136
__global__ __launch_bounds__(256)
void k_gin(const ushort_t* __restrict__ A, const ushort_t* __restrict__ W1T,
           const ushort_t* __restrict__ W2T, const float* __restrict__ b1,
           const float* __restrict__ b2, ushort_t* __restrict__ z2h,
           float* __restrict__ partS, float* __restrict__ partQ) {
    __shared__ ushort_t As[128 * GLDK];   // A tile, later reused for z1 (A-layout)
    __shared__ ushort_t Ws[64 * GLDK];    // weight chunk (64 output-cols x K=128)
    __shared__ float sS[128], sQ[128];
    const int tid = threadIdx.x;
    const int w = tid >> 6, l = tid & 63;
    const int lm = l & 15, lq = l >> 4;
    const int rw0 = w * 32;               // wave's 32-row strip
    const int vr0 = blockIdx.x * 128;
    if (tid < 128) { sS[tid] = 0.f; sQ[tid] = 0.f; }

    // stage A tile (K=128 all at once)
#pragma unroll
    for (int it = 0; it < 8; ++it) {
        int f = it * 256 + tid;           // 2048 16B slots
        int row = f >> 4, sl = f & 15;
        uint4 a = make_uint4(0, 0, 0, 0);
        int vr = vr0 + row;
        if (vr < NN) a = *(const uint4*)&A[(size_t)vr * HD + sl * 8];
        *(uint4*)&As[row * GLDK + sl * 8] = a;
    }

    // phase 1: z1 = A @ W1 (col chunks of 64)
    f32x4 z1a[2][2][4] = {};
    for (int c = 0; c < 2; ++c) {
        __syncthreads();
#pragma unroll
        for (int it = 0; it < 4; ++it) {
            int f = it * 256 + tid;
            int row = f >> 4, sl = f & 15;
            *(uint4*)&Ws[row * GLDK + sl * 8] =
                *(const uint4*)&W1T[(size_t)(c * 64 + row) * HD + sl * 8];
        }
        __syncthreads();
#pragma unroll
        for (int kk = 0; kk < 128; kk += 32) {
            f16x8 af[2], bf[4];
#pragma unroll
            for (int i = 0; i < 2; ++i)
                af[i] = *(const f16x8*)&As[(rw0 + i * 16 + lm) * GLDK + kk + lq * 8];
#pragma unroll
            for (int j = 0; j < 4; ++j)
                bf[j] = *(const f16x8*)&Ws[(j * 16 + lm) * GLDK + kk + lq * 8];
#pragma unroll
            for (int i = 0; i < 2; ++i)
#pragma unroll
                for (int j = 0; j < 4; ++j)
                    z1a[c][i][j] = __builtin_amdgcn_mfma_f32_16x16x32_f16(af[i], bf[j], z1a[c][i][j], 0, 0, 0);
        }
    }
    __syncthreads();                       // all A reads done; safe to overwrite with z1

    // write z1 = relu(z1a + b1) back into As in A-fragment layout (wave-private rows)
#pragma unroll
    for (int c = 0; c < 2; ++c)
#pragma unroll
        for (int j = 0; j < 4; ++j) {
            int col = c * 64 + j * 16 + lm;
            float bj = b1[col];
#pragma unroll
            for (int i = 0; i < 2; ++i)
#pragma unroll
                for (int r = 0; r < 4; ++r) {
                    int row = rw0 + i * 16 + lq * 4 + r;
                    As[row * GLDK + col] = f2h(fmaxf(z1a[c][i][j][r] + bj, 0.f));
                }
        }

    // phase 2: z2 = z1 @ W2
    f32x4 z2a[2][2][4] = {};
    for (int c2 = 0; c2 < 2; ++c2) {
        __syncthreads();
#pragma unroll
        for (int it = 0; it < 4; ++it) {
            int f = it * 256 + tid;
            int row = f >> 4, sl = f & 15;
            *(uint4*)&Ws[row * GLDK + sl * 8] =
                *(const uint4*)&W2T[(size_t)(c2 * 64 + row) * HD + sl * 8];
        }
        __syncthreads();
#pragma unroll
        for (int kk = 0; kk < 128; kk += 32) {
            f16x8 af[2], bf[4];
#pragma unroll
            for (int i = 0; i < 2; ++i)
                af[i] = *(const f16x8*)&As[(rw0 + i * 16 + lm) * GLDK + kk + lq * 8];
#pragma unroll
            for (int j = 0; j < 4; ++j)
                bf[j] = *(const f16x8*)&Ws[(j * 16 + lm) * GLDK + kk + lq * 8];
#pragma unroll
            for (int i = 0; i < 2; ++i)
#pragma unroll
                for (int j = 0; j < 4; ++j)
                    z2a[c2][i][j] = __builtin_amdgcn_mfma_f32_16x16x32_f16(af[i], bf[j], z2a[c2][i][j], 0, 0, 0);
        }
    }

    // epilogue: bias + fp16 store + BN partial stats
    float ls[2][4] = {}, lsq[2][4] = {};
#pragma unroll
    for (int c2 = 0; c2 < 2; ++c2)
#pragma unroll
        for (int j = 0; j < 4; ++j) {
            int col = c2 * 64 + j * 16 + lm;
            float bj = b2[col];
#pragma unroll
            for (int i = 0; i < 2; ++i)
#pragma unroll
                for (int r = 0; r < 4; ++r) {
                    int vr = vr0 + rw0 + i * 16 + lq * 4 + r;
                    if (vr < NN) {
                        float x = z2a[c2][i][j][r] + bj;
                        ls[c2][j] += x; lsq[c2][j] += x * x;
                        z2h[(size_t)vr * HD + col] = f2h(x);
                    }
                }
        }
#pragma unroll
    for (int c2 = 0; c2 < 2; ++c2)
#pragma unroll
        for (int j = 0; j < 4; ++j) {
            atomicAdd(&sS[c2 * 64 + j * 16 + lm], ls[c2][j]);
            atomicAdd(&sQ[c2 * 64 + j * 16 + lm], lsq[c2][j]);
        }
    __syncthreads();
    if (tid < 128) {
        partS[(size_t)tid * NBM + blockIdx.x] = sS[tid];
        partQ[(size_t)tid * NBM + blockIdx.x] = sQ[tid];
    }
}

// ---------------- fused FFN (256 threads, 32-row strips):
// h_mid = (A0∘t+B0) + relu(A1∘z2+B1) staged in LDS; f1 kept in LDS per 64-col
// chunk (never hits HBM); t_new = f1@W4 + b4 + h_mid. Fs rows are wave-private. ----------------
#define FLDK 72
__global__ __launch_bounds__(256)
void k_ffn(ushort_t* __restrict__ th, const ushort_t* __restrict__ z2h,
           const ushort_t* __restrict__ W3T, const float* __restrict__ b3,
           const ushort_t* __restrict__ W4T, const float* __restrict__ b4,
           const float* __restrict__ bnA0, const float* __restrict__ bnB0,
           const float* __restrict__ bnA1, const float* __restrict__ bnB1,
           float* __restrict__ partS, float* __restrict__ partQ) {
    __shared__ ushort_t As[128 * GLDK];   // h_mid tile (A of GEMM1 + residual source)
    __shared__ ushort_t Fs[128 * FLDK];   // f1 chunk (A of GEMM2), wave-private rows
    __shared__ ushort_t Ws[128 * FLDK];   // W3 chunk (64x128 @GLDK) or W4 chunk (128x64 @FLDK)
    __shared__ float sS[128], sQ[128];
    __shared__ float sA0[128], sB0[128], sA1[128], sB1[128];
    const int tid = threadIdx.x;
    const int w = tid >> 6, l = tid & 63;
    const int lm = l & 15, lq = l >> 4;
    const int rw0 = w * 32;
    const int vr0 = blockIdx.x * 128;

    if (tid < 128) {
        sS[tid] = 0.f; sQ[tid] = 0.f;
        sA0[tid] = bnA0[tid]; sB0[tid] = bnB0[tid];
        sA1[tid] = bnA1[tid]; sB1[tid] = bnB1[tid];
    }
    __syncthreads();

    // stage h_mid into As (fp16)
#pragma unroll
    for (int it = 0; it < 8; ++it) {
        int f = it * 256 + tid;           // 2048 16B slots
        int row = f >> 4, sl = f & 15;
        int vr = vr0 + row;
        uint4 o = make_uint4(0, 0, 0, 0);
        if (vr < NN) {
            uint4 tv = *(const uint4*)&th[(size_t)vr * HD + sl * 8];
            uint4 zv = *(const uint4*)&z2h[(size_t)vr * HD + sl * 8];
            uint_t tu[4] = {tv.x, tv.y, tv.z, tv.w};
            uint_t zu[4] = {zv.x, zv.y, zv.z, zv.w};
            uint_t ou[4];
#pragma unroll
            for (int m = 0; m < 4; ++m) {
                int ch0 = sl * 8 + m * 2;
                float t0 = h2f((ushort_t)(tu[m] & 0xFFFFu));
                float t1 = h2f((ushort_t)(tu[m] >> 16));
                float z0 = h2f((ushort_t)(zu[m] & 0xFFFFu));
                float z1 = h2f((ushort_t)(zu[m] >> 16));
                float h0 = sA0[ch0] * t0 + sB0[ch0] + fmaxf(sA1[ch0] * z0 + sB1[ch0], 0.f);
                float h1 = sA0[ch0 + 1] * t1 + sB0[ch0 + 1] + fmaxf(sA1[ch0 + 1] * z1 + sB1[ch0 + 1], 0.f);
                ou[m] = (uint_t)f2h(h0) | ((uint_t)f2h(h1) << 16);
            }
            o = make_uint4(ou[0], ou[1], ou[2], ou[3]);
        }
        *(uint4*)&As[row * GLDK + sl * 8] = o;
    }

    f32x4 acc2[2][2][4] = {};   // ffn2 acc: [out-col-chunk][row frag][col frag]
    for (int kc = 0; kc < 4; ++kc) {
        // ---- GEMM1: f1_kc = relu(h_mid @ W3[:, kc*64..+64) + b3) into Fs ----
        __syncthreads();                   // prior Ws readers done (and As staged, 1st iter)
#pragma unroll
        for (int it = 0; it < 4; ++it) {
            int f = it * 256 + tid;
            int row = f >> 4, sl = f & 15; // 64 rows x 128 k
            *(uint4*)&Ws[row * GLDK + sl * 8] =
                *(const uint4*)&W3T[(size_t)(kc * 64 + row) * HD + sl * 8];
        }
        __syncthreads();
        f32x4 f1a[2][4] = {};
#pragma unroll
        for (int kk = 0; kk < 128; kk += 32) {
            f16x8 af[2], bf[4];
#pragma unroll
            for (int i = 0; i < 2; ++i)
                af[i] = *(const f16x8*)&As[(rw0 + i * 16 + lm) * GLDK + kk + lq * 8];
#pragma unroll
            for (int j = 0; j < 4; ++j)
                bf[j] = *(const f16x8*)&Ws[(j * 16 + lm) * GLDK + kk + lq * 8];
#pragma unroll
            for (int i = 0; i < 2; ++i)
#pragma unroll
                for (int j = 0; j < 4; ++j)
                    f1a[i][j] = __builtin_amdgcn_mfma_f32_16x16x32_f16(af[i], bf[j], f1a[i][j], 0, 0, 0);
        }
        // write relu(f1+b3) into Fs in A-fragment layout (wave-private rows)
#pragma unroll
        for (int j = 0; j < 4; ++j) {
            int fcol = j * 16 + lm;
            float bj = b3[kc * 64 + fcol];
#pragma unroll
            for (int i = 0; i < 2; ++i)
#pragma unroll
                for (int r = 0; r < 4; ++r) {
                    int row = rw0 + i * 16 + lq * 4 + r;
                    Fs[row * FLDK + fcol] = f2h(fmaxf(f1a[i][j][r] + bj, 0.f));
                }
        }
        // ---- GEMM2 partial: acc2 += Fs @ W4[kc*64..+64, :] ----
        __syncthreads();                   // all waves done reading Ws (W3)
#pragma unroll
        for (int it = 0; it < 4; ++it) {
            int f = it * 256 + tid;
            int row = f >> 3, sl = f & 7;  // 128 out-cols x 64 k
            *(uint4*)&Ws[row * FLDK + sl * 8] =
                *(const uint4*)&W4T[(size_t)row * 256 + kc * 64 + sl * 8];
        }
        __syncthreads();
#pragma unroll
        for (int kk = 0; kk < 64; kk += 32) {
            f16x8 af[2];
#pragma unroll
            for (int i = 0; i < 2; ++i)
                af[i] = *(const f16x8*)&Fs[(rw0 + i * 16 + lm) * FLDK + kk + lq * 8];
#pragma unroll
            for (int c2 = 0; c2 < 2; ++c2)
#pragma unroll
                for (int j = 0; j < 4; ++j) {
                    f16x8 bf = *(const f16x8*)&Ws[(c2 * 64 + j * 16 + lm) * FLDK + kk + lq * 8];
#pragma unroll
                    for (int i = 0; i < 2; ++i)
                        acc2[c2][i][j] = __builtin_amdgcn_mfma_f32_16x16x32_f16(af[i], bf, acc2[c2][i][j], 0, 0, 0);
                }
        }
    }

    // epilogue: x = acc2 + b4 + h_mid(LDS fp16); write th + BN partial stats
    float ls[2][4] = {}, lsq[2][4] = {};
#pragma unroll
    for (int c2 = 0; c2 < 2; ++c2)
#pragma unroll
        for (int j = 0; j < 4; ++j) {
            int col = c2 * 64 + j * 16 + lm;
            float bj = b4[col];
#pragma unroll
            for (int i = 0; i < 2; ++i)
#pragma unroll
                for (int r = 0; r < 4; ++r) {
                    int lrow = rw0 + i * 16 + lq * 4 + r;
                    int vr = vr0 + lrow;
                    if (vr < NN) {
                        float resv = h2f(As[lrow * GLDK + col]);
                        float x = acc2[c2][i][j][r] + bj + resv;
                        ls[c2][j] += x; lsq[c2][j] += x * x;
                        th[(size_t)vr * HD + col] = f2h(x);
                    }
                }
        }
#pragma unroll
    for (int c2 = 0; c2 < 2; ++c2)
#pragma unroll
        for (int j = 0; j < 4; ++j) {
            atomicAdd(&sS[c2 * 64 + j * 16 + lm], ls[c2][j]);
            atomicAdd(&sQ[c2 * 64 + j * 16 + lm], lsq[c2][j]);
        }
    __syncthreads();
    if (tid < 128) {
        partS[(size_t)tid * NBM + blockIdx.x] = sS[tid];
        partQ[(size_t)tid * NBM + blockIdx.x] = sQ[tid];
    }
}

// reduce per-block partial sums -> per-channel BN scale/shift: y = x*bnA[c] + bnB[c]
__global__ void k_bnparm(const float* __restrict__ partS, const float* __restrict__ partQ,
                         const float* __restrict__ g, const float* __restrict__ b,
                         float* __restrict__ bnA, float* __restrict__ bnB) {
    __shared__ float smS[256], smQ[256];
    int c = blockIdx.x, t = threadIdx.x;
    float s = 0.f, q = 0.f;
    for (int i = t; i < NBM; i += 256) {
        s += partS[(size_t)c * NBM + i];
        q += partQ[(size_t)c * NBM + i];
    }
    smS[t] = s; smQ[t] = q; __syncthreads();
    for (int st = 128; st > 0; st >>= 1) {
        if (t < st) { smS[t] += smS[t + st]; smQ[t] += smQ[t + st]; }
        __syncthreads();
    }
    if (t == 0) {
        float mu = smS[0] * (1.0f / NN);
        float var = smQ[0] * (1.0f / NN) - mu * mu;
        float inv = rsqrtf(var + BNEPS);
        float a = g[c] * inv;
        bnA[c] = a;
        bnB[c] = b[c] - mu * a;
    }
}

// pooling over raw th: gsum[g] = sum_v t[v]; affine applied in k_head
__global__ void k_pool(const uint2* __restrict__ th4, const int* __restrict__ goff,
                       const int* __restrict__ cnt, float* __restrict__ gsum) {
    __shared__ float4 sm[256];
    int g = blockIdx.x >> 2, sub = blockIdx.x & 3;
    int n0 = goff[g], n = cnt[g];
    int cg = threadIdx.x & 31, rl = threadIdx.x >> 5;  // rl 0..7
    float4 acc = make_float4(0.f, 0.f, 0.f, 0.f);
    for (int r = sub * 8 + rl; r < n; r += 32) {
        uint2 v = th4[(size_t)(n0 + r) * 32 + cg];
        acc.x += h2f((ushort_t)(v.x & 0xFFFFu));
        acc.y += h2f((ushort_t)(v.x >> 16));
        acc.z += h2f((ushort_t)(v.y & 0xFFFFu));
        acc.w += h2f((ushort_t)(v.y >> 16));
    }
    sm[threadIdx.x] = acc; __syncthreads();
    for (int st = 128; st >= 32; st >>= 1) {
        if (threadIdx.x < st) {
            float4 o = sm[threadIdx.x + st];
            sm[threadIdx.x].x += o.x; sm[threadIdx.x].y += o.y;
            sm[threadIdx.x].z += o.z; sm[threadIdx.x].w += o.w;
        }
        __syncthreads();
    }
    if (threadIdx.x < 32) {
        float4 v = sm[threadIdx.x];
        atomicAdd(&gsum[g * HD + cg * 4 + 0], v.x);
        atomicAdd(&gsum[g * HD + cg * 4 + 1], v.y);
        atomicAdd(&gsum[g * HD + cg * 4 + 2], v.z);
        atomicAdd(&gsum[g * HD + cg * 4 + 3], v.w);
    }
}

__global__ void k_head(const float* __restrict__ gsum, const int* __restrict__ cnt,
                       const float* __restrict__ bnA0, const float* __restrict__ bnB0,
                       const float* __restrict__ w1, const float* __restrict__ b1,
                       const float* __restrict__ w2, const float* __restrict__ b2,
                       float* __restrict__ out) {
    __shared__ float gv[HD], av[HD];
    int gid = blockIdx.x, t = threadIdx.x;
    float c = fmaxf((float)cnt[gid], 1.0f);
    gv[t] = bnA0[t] * (gsum[gid * HD + t] / c) + bnB0[t];   // mean then affine
    __syncthreads();
    float a = b1[t];
    for (int k = 0; k < HD; ++k) a += gv[k] * w1[k * HD + t];
    av[t] = fmaxf(a, 0.f);
    __syncthreads();
    if (t < NOUT) {
        float o = b2[t];
        for (int k = 0; k < HD; ++k) o += av[k] * w2[k * NOUT + t];
        out[gid * NOUT + t] = o;
    }
}

// ---------------- workspace layout ----------------
// z2h keeps a DEDICATED region (round-6 race lesson). aggh/epair share one
// arena (aggh 25.6MB >= epair 12.8MB; epair dead before first k_aggb).
static constexpr size_t AL(size_t x) { return (x + 511) & ~(size_t)511; }
static constexpr size_t OFF_TH     = 0;                                         // fp16 t (BN input)
static constexpr size_t OFF_SHARE  = OFF_TH     + AL((size_t)NN * HD * 2);
static constexpr size_t SZ_SHARE   = AL((size_t)NN * HD * 2);                   // aggh | epair
static constexpr size_t OFF_Z2     = OFF_SHARE  + SZ_SHARE;                     // z2h fp16 (dedicated)
static constexpr size_t OFF_RW     = OFF_Z2     + AL((size_t)NN * HD * 2);
static constexpr size_t OFF_P0     = OFF_RW     + AL((size_t)WLK * NN * 4);
static constexpr size_t OFF_P1     = OFF_P0     + AL((size_t)NN * 4);
static constexpr size_t OFF_PD0    = OFF_P1     + AL((size_t)NN * 4);
static constexpr size_t OFF_PD1    = OFF_PD0    + AL((size_t)NN * 4);
static constexpr size_t OFF_DINV   = OFF_PD1    + AL((size_t)NN * 4);
static constexpr size_t OFF_ESRC   = OFF_DINV   + AL((size_t)NN * 4);
static constexpr size_t OFF_ROWPTR = OFF_ESRC   + AL((size_t)NE * 4);
static constexpr size_t OFF_DEG    = OFF_ROWPTR + AL((size_t)(NN + 1) * 4);
static constexpr size_t OFF_BHIST  = OFF_DEG    + AL((size_t)NN * 4);
static constexpr size_t OFF_BOFFS  = OFF_BHIST  + AL((size_t)NSCAN * 4);
static constexpr size_t OFF_BSUM   = OFF_BOFFS  + AL((size_t)NSCAN * 4);
static constexpr size_t OFF_WT1    = OFF_BSUM   + AL(512 * 4);
static constexpr size_t OFF_WT2    = OFF_WT1    + AL((size_t)5 * 16384 * 2);
static constexpr size_t OFF_WT3    = OFF_WT2    + AL((size_t)5 * 16384 * 2);
static constexpr size_t OFF_WT4    = OFF_WT3    + AL((size_t)5 * 32768 * 2);
static constexpr size_t OFF_PARTS  = OFF_WT4    + AL((size_t)5 * 32768 * 2);
static constexpr size_t OFF_PARTQ  = OFF_PARTS  + AL((size_t)128 * NBM * 4);
static constexpr size_t OFF_BNA0   = OFF_PARTQ  + AL((size_t)128 * NBM * 4);
static constexpr size_t OFF_BNB0   = OFF_BNA0   + AL(128 * 4);
static constexpr size_t OFF_BNA1   = OFF_BNB0   + AL(128 * 4);
static constexpr size_t OFF_BNB1   = OFF_BNA1   + AL(128 * 4);
static constexpr size_t OFF_M      = OFF_BNB1   + AL(128 * 4);
static constexpr size_t OFF_C1     = OFF_M      + AL((size_t)WLK * HD * 4);
static constexpr size_t OFF_CNT    = OFF_C1     + AL(HD * 4);
static constexpr size_t OFF_GOFF   = OFF_CNT    + AL(NG * 4);
static constexpr size_t OFF_GSUM   = OFF_GOFF   + AL(NG * 4);
static constexpr size_t ZERO_BYTES = (size_t)NG * HD * 4;                        // gsum only

extern "C" void kernel_launch(void* const* d_in, const int* in_sizes, int n_in,
                              void* d_out, int out_size, void* d_ws, size_t ws_size,
                              hipStream_t stream) {
    const int* eidx = (const int*)d_in[1];
    const int* row0 = eidx;
    const int* col0 = eidx + NE;
    const int* batch = (const int*)d_in[2];
    const float* emb = (const float*)d_in[3];
    const float* pe_w = (const float*)d_in[4];
    const float* pe_b = (const float*)d_in[5];
    const float* proj_w = (const float*)d_in[6];
    const float* proj_b = (const float*)d_in[7];
    const float* gin_w1 = (const float*)d_in[8];
    const float* gin_b1 = (const float*)d_in[9];
    const float* gin_w2 = (const float*)d_in[10];
    const float* gin_b2 = (const float*)d_in[11];
    const float* bn_g = (const float*)d_in[12];
    const float* bn_b = (const float*)d_in[13];
    const float* ffn_w1 = (const float*)d_in[14];
    const float* ffn_b1 = (const float*)d_in[15];
    const float* ffn_w2 = (const float*)d_in[16];
    const float* ffn_b2 = (const float*)d_in[17];
    const float* ffn_bn_g = (const float*)d_in[18];
    const float* ffn_bn_b = (const float*)d_in[19];
    const float* out_w1 = (const float*)d_in[20];
    const float* out_b1 = (const float*)d_in[21];
    const float* out_w2 = (const float*)d_in[22];
    const float* out_b2 = (const float*)d_in[23];
    float* out = (float*)d_out;

    char* ws = (char*)d_ws;
    ushort_t* th    = (ushort_t*)(ws + OFF_TH);
    ushort_t* aggh  = (ushort_t*)(ws + OFF_SHARE);
    int2*     epair = (int2*)(ws + OFF_SHARE);
    ushort_t* z2h   = (ushort_t*)(ws + OFF_Z2);
    float*    rw    = (float*)(ws + OFF_RW);
    float*    p0    = (float*)(ws + OFF_P0);
    float*    p1    = (float*)(ws + OFF_P1);
    float*    pd0   = (float*)(ws + OFF_PD0);
    float*    pd1   = (float*)(ws + OFF_PD1);
    float*    dinv  = (float*)(ws + OFF_DINV);
    int*      esrc  = (int*)(ws + OFF_ESRC);
    int*      rowptr= (int*)(ws + OFF_ROWPTR);
    int*      deg   = (int*)(ws + OFF_DEG);
    int*      bhist = (int*)(ws + OFF_BHIST);
    int*      boffs = (int*)(ws + OFF_BOFFS);
    int*      bsum  = (int*)(ws + OFF_BSUM);
    ushort_t* wt1   = (ushort_t*)(ws + OFF_WT1);
    ushort_t* wt2   = (ushort_t*)(ws + OFF_WT2);
    ushort_t* wt3   = (ushort_t*)(ws + OFF_WT3);
    ushort_t* wt4   = (ushort_t*)(ws + OFF_WT4);
    float*    partS = (float*)(ws + OFF_PARTS);
    float*    partQ = (float*)(ws + OFF_PARTQ);
    float*    bnA0  = (float*)(ws + OFF_BNA0);
    float*    bnB0  = (float*)(ws + OFF_BNB0);
    float*    bnA1  = (float*)(ws + OFF_BNA1);
    float*    bnB1  = (float*)(ws + OFF_BNB1);
    float*    M     = (float*)(ws + OFF_M);
    float*    c1    = (float*)(ws + OFF_C1);
    int*      cnt   = (int*)(ws + OFF_CNT);
    int*      goff  = (int*)(ws + OFF_GOFF);
    float*    gsum  = (float*)(ws + OFF_GSUM);

    const int NB = CDIV(NN, 256);        // 391
    const int NBV = CDIV(NN * 32, 256);  // 12500

    hipMemsetAsync(ws + OFF_GSUM, 0, ZERO_BYTES, stream);

    // ---- atomic-free CSR build ----
    k_cnt<<<1, 128, 0, stream>>>(batch, cnt, goff);
    k_bhist<<<NEB, 256, 0, stream>>>(col0, bhist);
    k_gscan1<<<NSB, 256, 0, stream>>>(bhist, bsum);
    k_scan2<<<1, 512, 0, stream>>>(bsum, NSB);
    k_gscan3<<<NSB, 256, 0, stream>>>(bhist, bsum, boffs);
    k_escatter<<<NEB, 256, 0, stream>>>(row0, col0, boffs, epair);
    k_bucket<<<NBKT, 256, 0, stream>>>(epair, boffs, rowptr, deg, esrc);

    // ---- PE + projection ----
    k_init_pe<<<NB, 256, 0, stream>>>(deg, batch, cnt, dinv, p0, pd0);
    k_mc1<<<1, 128, 0, stream>>>(emb, pe_w, pe_b, proj_w, proj_b, M, c1, bnA0, bnB0);
    k_prepw<<<1920, 256, 0, stream>>>(gin_w1, gin_w2, ffn_w1, ffn_w2, wt1, wt2, wt3, wt4);
    for (int s = 0; s < WLK; ++s) {
        const float* pin = (s & 1) ? p1 : p0;
        const float* pdin = (s & 1) ? pd1 : pd0;
        float* pout = (s & 1) ? p0 : p1;
        float* pdout = (s & 1) ? pd0 : pd1;
        k_rw_step<<<NB, 256, 0, stream>>>(pin, pdin, rowptr, esrc, dinv,
                                          rw + (size_t)s * NN, pout, pdout);
    }
    k_proj<<<NBV, 256, 0, stream>>>(rw, M, c1, (uint2*)th);

    // ---- layers: gather | GIN-MLP | bnparm | fused-FFN | bnparm ----
    for (int i = 0; i < NL; ++i) {
        k_aggb<<<CDIV(NN, 4), 256, 0, stream>>>((const uint_t*)th, rowptr, esrc,
                                                bnA0, bnB0, (uint_t*)aggh);
        k_gin<<<NBM, 256, 0, stream>>>(aggh, wt1 + (size_t)i * 16384, wt2 + (size_t)i * 16384,
                                       gin_b1 + i * HD, gin_b2 + i * HD, z2h, partS, partQ);
        k_bnparm<<<128, 256, 0, stream>>>(partS, partQ, bn_g + i * HD, bn_b + i * HD, bnA1, bnB1);
        k_ffn<<<NBM, 256, 0, stream>>>(th, z2h, wt3 + (size_t)i * 32768, ffn_b1 + i * 256,
                                       wt4 + (size_t)i * 32768, ffn_b2 + i * HD,
                                       bnA0, bnB0, bnA1, bnB1, partS, partQ);
        k_bnparm<<<128, 256, 0, stream>>>(partS, partQ, ffn_bn_g + i * HD, ffn_bn_b + i * HD,
                                          bnA0, bnB0);
    }

    k_pool<<<NG * 4, 256, 0, stream>>>((const uint2*)th, goff, cnt, gsum);
    k_head<<<NG, 128, 0, stream>>>(gsum, cnt, bnA0, bnB0, out_w1, out_b1, out_w2, out_b2, out);
}